// Round 17
// baseline (226.480 us; speedup 1.0000x reference)
//
#include <hip/hip_runtime.h>

#define C 16
#define TAPS 27
#define NCONV 17
#define LISTCAP 98304
#define NPAIR 14
#define NBRICK 13824  // 24^3 bricks of 4^3

typedef _Float16 half8 __attribute__((ext_vector_type(8)));
typedef _Float16 half4 __attribute__((ext_vector_type(4)));
typedef float f32x4 __attribute__((ext_vector_type(4)));

// ---- prep: x NCDHW->NDHWC fp16, zero P1h, weights, m48, brick counts ----
// Wh[l][pair][lane][8]: lane co=lane&15, g=lane>>4; k=8g+j; ci=k&15; tap=2p+(k>>4).
__global__ void prep_kernel(const float* __restrict__ x, const int* __restrict__ mask_idx,
                            _Float16* __restrict__ P0h, _Float16* __restrict__ P1h,
                            const float* __restrict__ W, _Float16* __restrict__ Wh,
                            int* __restrict__ counts, float* __restrict__ m48) {
    const int n96 = 96 * 96 * 96;
    int b = blockIdx.x;
    if (b < 3456) {
        int v = b * 256 + threadIdx.x;  // n96 == 3456*256 exactly
        half8 h0, h1;
#pragma unroll
        for (int c = 0; c < 8; c++) h0[c] = (_Float16)x[(long)c * n96 + v];
#pragma unroll
        for (int c = 0; c < 8; c++) h1[c] = (_Float16)x[(long)(c + 8) * n96 + v];
        half8* dp = reinterpret_cast<half8*>(P0h + (long)v * C);
        dp[0] = h0;
        dp[1] = h1;
        half8 zz = {};
        half8* zp = reinterpret_cast<half8*>(P1h + (long)v * C);
        zp[0] = zz;
        zp[1] = zz;
    } else if (b < 3456 + 476) {
        int i = (b - 3456) * 256 + threadIdx.x;
        const int total = NCONV * NPAIR * 64 * 8;
        if (i < total) {
            int j = i & 7;
            int lane = (i >> 3) & 63;
            int p = (i >> 9) % NPAIR;
            int l = (i >> 9) / NPAIR;
            int co = lane & 15;
            int g = lane >> 4;
            int k = 8 * g + j;
            int ci = k & 15;
            int tap = 2 * p + (k >> 4);
            float val = (tap < TAPS) ? W[((l * C + co) * C + ci) * TAPS + tap] : 0.f;
            Wh[i] = (_Float16)val;
        }
    } else if (b < 3456 + 476 + 432) {
        // m48: thread per voxel, 3^3 window over mask_idx at [2c-1, 2c+1]
        int i = (b - 3456 - 476) * 256 + threadIdx.x;  // 432*256 == 110592 exactly
        int xx = i % 48, yy = (i / 48) % 48, zc = i / (48 * 48);
        float m = 0.f;
        for (int dz = 0; dz < 3; dz++) {
            int z2 = 2 * zc - 1 + dz;
            if ((unsigned)z2 >= 96u) continue;
            for (int dy = 0; dy < 3; dy++) {
                int y2 = 2 * yy - 1 + dy;
                if ((unsigned)y2 >= 96u) continue;
                for (int dx = 0; dx < 3; dx++) {
                    int x2 = 2 * xx - 1 + dx;
                    if ((unsigned)x2 >= 96u) continue;
                    if (mask_idx[((long)z2 * 96 + y2) * 96 + x2] == 0) m = 1.f;
                }
            }
        }
        m48[i] = m;
    } else {
        // brick counts: wave per 4x4x4 brick, lane = voxel-in-brick
        int wid = threadIdx.x >> 6, lane = threadIdx.x & 63;
        int brick = (b - 3456 - 476 - 432) * 4 + wid;  // 3456*4 == NBRICK
        int bx = brick % 24, by = (brick / 24) % 24, bz = brick / (24 * 24);
        int xx = bx * 4 + (lane & 3);
        int yy = by * 4 + ((lane >> 2) & 3);
        int zz = bz * 4 + (lane >> 4);
        int act = (mask_idx[((long)zz * 96 + yy) * 96 + xx] == 0);
        unsigned long long bl = __ballot(act);
        if (lane == 0) counts[brick] = __popcll(bl);
    }
}

__global__ void scan_kernel(const int* __restrict__ counts, int* __restrict__ offsets,
                            int* __restrict__ nact, int nb) {
    __shared__ int s[256];
    int t = threadIdx.x;
    const int CH = (nb + 255) / 256;
    int base = t * CH, sum = 0;
    for (int j = 0; j < CH; j++)
        if (base + j < nb) sum += counts[base + j];
    s[t] = sum;
    __syncthreads();
    for (int off = 1; off < 256; off <<= 1) {
        int v = (t >= off) ? s[t - off] : 0;
        __syncthreads();
        s[t] += v;
        __syncthreads();
    }
    int run = s[t] - sum;
    for (int j = 0; j < CH; j++) {
        if (base + j < nb) {
            offsets[base + j] = run;
            run += counts[base + j];
        }
    }
    if (t == 255) *nact = s[255];
}

// ---- brick-ordered scatter + pools (m24 3^3, m12 7^3, m6 15^3 — from m48) ----
__global__ void scatter_kernel(const int* __restrict__ mi, const int* __restrict__ offsets,
                               int* __restrict__ list, int cap, const float* __restrict__ m48,
                               float* __restrict__ m24, float* __restrict__ m12,
                               float* __restrict__ m6) {
    int b = blockIdx.x;
    int tid = threadIdx.x;
    if (b < 3456) {  // brick scatter: wave per brick
        int wid = tid >> 6, lane = tid & 63;
        int brick = b * 4 + wid;
        int bx = brick % 24, by = (brick / 24) % 24, bz = brick / (24 * 24);
        int xx = bx * 4 + (lane & 3);
        int yy = by * 4 + ((lane >> 2) & 3);
        int zz = bz * 4 + (lane >> 4);
        int v = ((zz * 96 + yy) * 96 + xx);
        int act = (mi[v] == 0);
        unsigned long long bl = __ballot(act);
        int rank = __popcll(bl & ((1ull << lane) - 1));
        if (act) {
            int pos = offsets[brick] + rank;
            if (pos < cap) list[pos] = v;
        }
    } else if (b < 3456 + 54) {  // m24: thread/voxel, 3^3 over m48
        int i = (b - 3456) * 256 + tid;
        if (i < 24 * 24 * 24) {
            int x = i % 24, y = (i / 24) % 24, z = i / (24 * 24);
            float m = 0.f;
            for (int dz = 0; dz < 3; dz++) {
                int zz = 2 * z - 1 + dz;
                if ((unsigned)zz >= 48u) continue;
                for (int dy = 0; dy < 3; dy++) {
                    int yy = 2 * y - 1 + dy;
                    if ((unsigned)yy >= 48u) continue;
                    for (int dx = 0; dx < 3; dx++) {
                        int xx = 2 * x - 1 + dx;
                        if ((unsigned)xx >= 48u) continue;
                        m = fmaxf(m, m48[((long)zz * 48 + yy) * 48 + xx]);
                    }
                }
            }
            m24[i] = m;
        }
    } else if (b < 3456 + 54 + 432) {  // m12: wave/voxel, 7^3 over m48 at [4c-3,4c+3]
        int wv = (b - 3456 - 54) * 4 + (tid >> 6);
        int lane = tid & 63;
        int x = wv % 12, y = (wv / 12) % 12, z = wv / 144;
        float m = 0.f;
        for (int k = lane; k < 343; k += 64) {
            int dz = k / 49, r = k % 49, dy = r / 7, dx = r % 7;
            int zz = 4 * z - 3 + dz, yy = 4 * y - 3 + dy, xx = 4 * x - 3 + dx;
            if ((unsigned)zz < 48u && (unsigned)yy < 48u && (unsigned)xx < 48u)
                m = fmaxf(m, m48[((long)zz * 48 + yy) * 48 + xx]);
        }
        for (int off = 32; off; off >>= 1) m = fmaxf(m, __shfl_xor(m, off));
        if (lane == 0 && wv < 1728) m12[wv] = m;
    } else {  // m6: wave/voxel, 15^3 over m48 at [8c-7,8c+7]
        int wv = (b - 3456 - 54 - 432) * 4 + (tid >> 6);
        int lane = tid & 63;
        int x = wv % 6, y = (wv / 6) % 6, z = wv / 36;
        float m = 0.f;
        for (int k = lane; k < 3375; k += 64) {
            int dz = k / 225, r = k % 225, dy = r / 15, dx = r % 15;
            int zz = 8 * z - 7 + dz, yy = 8 * y - 7 + dy, xx = 8 * x - 7 + dx;
            if ((unsigned)zz < 48u && (unsigned)yy < 48u && (unsigned)xx < 48u)
                m = fmaxf(m, m48[((long)zz * 48 + yy) * 48 + xx]);
        }
        for (int off = 32; off; off >>= 1) m = fmaxf(m, __shfl_xor(m, off));
        if (lane == 0 && wv < 216) m6[wv] = m;
    }
}

// ---- MFMA conv (r13-proven) + optional fused fp32 NCDHW output ----
template <int STRIDE, bool SPARSE, bool WF32>
__global__ __launch_bounds__(256) void mconv_kernel(
    const _Float16* __restrict__ in, _Float16* __restrict__ out,
    const float* __restrict__ mask, const int* __restrict__ list,
    const int* __restrict__ nact, const _Float16* __restrict__ Whl,
    const float* __restrict__ bs, const float* __restrict__ bb,
    int Din, int Dout, float* __restrict__ outf) {
    int n = Dout * Dout * Dout;
    int nv;
    if (SPARSE) {
        nv = *nact;
        if (nv > LISTCAP) nv = LISTCAP;
    } else {
        nv = n;
    }
    int tile = blockIdx.x * 4 + (threadIdx.x >> 6);
    if (tile * 16 >= nv) return;  // per-wave exit (no barriers)

    int lane = threadIdx.x & 63;
    int col = lane & 15;
    int g = lane >> 4;
    int s = tile * 16 + col;
    bool val = s < nv;
    int v = 0;
    if (SPARSE) {
        if (val) v = list[s];
    } else {
        v = val ? s : 0;
    }
    int x = v % Dout, y = (v / Dout) % Dout, z = v / (Dout * Dout);

    const half8* wf = reinterpret_cast<const half8*>(Whl);
    half8 a[NPAIR];
#pragma unroll
    for (int p = 0; p < NPAIR; p++) a[p] = wf[p * 64 + lane];

    int half_off = (g & 1) * 8;
    int tg = g >> 1;

    f32x4 acc = {0.f, 0.f, 0.f, 0.f};
#pragma unroll
    for (int p = 0; p < NPAIR; p++) {
        int tap = 2 * p + tg;
        if (tap > TAPS - 1) tap = TAPS - 1;  // dummy half: weights are 0
        int kz = tap / 9, ky = (tap / 3) % 3, kx = tap % 3;
        int zz = STRIDE * z - 1 + kz;
        int yy = STRIDE * y - 1 + ky;
        int xx = STRIDE * x - 1 + kx;
        bool ok = val && ((unsigned)zz < (unsigned)Din) && ((unsigned)yy < (unsigned)Din) &&
                  ((unsigned)xx < (unsigned)Din);
        half8 b = {};
        if (ok) {
            b = *reinterpret_cast<const half8*>(
                in + (long)((zz * Din + yy) * Din + xx) * C + half_off);
        }
        acc = __builtin_amdgcn_mfma_f32_16x16x32_f16(a[p], b, acc, 0, 0, 0);
    }

    if (val) {
        float mk = SPARSE ? 1.f : mask[v];
        int cob = g * 4;
        half4 r;
#pragma unroll
        for (int j = 0; j < 4; j++) {
            float t = fmaxf(acc[j] * bs[cob + j] + bb[cob + j], 0.f) * mk;
            r[j] = (_Float16)t;
            if (WF32) outf[(long)(cob + j) * n + v] = t;
        }
        *reinterpret_cast<half4*>(out + (long)v * C + cob) = r;
    }
}

extern "C" void kernel_launch(void* const* d_in, const int* in_sizes, int n_in,
                              void* d_out, int out_size, void* d_ws, size_t ws_size,
                              hipStream_t stream) {
    const float* x = (const float*)d_in[0];
    const int* mask_idx = (const int*)d_in[1];
    const float* W = (const float*)d_in[2];
    const float* bs = (const float*)d_in[3];
    const float* bb = (const float*)d_in[4];
    float* out = (float*)d_out;

    const int n96 = 96 * 96 * 96;
    const int n48 = 48 * 48 * 48;
    const int n24 = 24 * 24 * 24;
    const int n12 = 12 * 12 * 12;
    const int n6 = 6 * 6 * 6;

    _Float16* P0h = (_Float16*)d_ws;
    _Float16* P1h = P0h + (long)C * n96;
    float* m48 = (float*)(P1h + (long)C * n96);
    float* m24 = m48 + n48;
    float* m12 = m24 + n24;
    float* m6 = m12 + n12;
    _Float16* Wh = (_Float16*)(m6 + n6);  // [17][14][64][8]
    int* list = (int*)(Wh + (long)NCONV * NPAIR * 64 * 8);
    int* counts = list + LISTCAP;
    int* offsets = counts + NBRICK;
    int* nact = offsets + NBRICK;

    // 1. prep (transpose + zero + weights + m48 + brick counts)
    hipLaunchKernelGGL(prep_kernel, dim3(3456 + 476 + 432 + 3456), dim3(256), 0, stream,
                       x, mask_idx, P0h, P1h, W, Wh, counts, m48);
    // 2. scan over bricks
    hipLaunchKernelGGL(scan_kernel, dim3(1), dim3(256), 0, stream, counts, offsets, nact, NBRICK);
    // 3. brick-ordered scatter + pools
    hipLaunchKernelGGL(scatter_kernel, dim3(3456 + 54 + 432 + 54), dim3(256), 0, stream,
                       mask_idx, offsets, list, LISTCAP, m48, m24, m12, m6);

    auto mblk = [&](long nvox) { return dim3((unsigned)((nvox + 63) / 64)); };
    auto WL = [&](int l) { return Wh + (long)l * NPAIR * 64 * 8; };

    // 4-5. sparse 96 level
    hipLaunchKernelGGL((mconv_kernel<1, true, false>), mblk(LISTCAP), dim3(256), 0, stream,
                       P0h, P1h, (const float*)nullptr, list, nact, WL(0), bs, bb, 96, 96,
                       (float*)nullptr);
    hipLaunchKernelGGL((mconv_kernel<1, true, false>), mblk(LISTCAP), dim3(256), 0, stream,
                       P1h, P0h, (const float*)nullptr, list, nact, WL(1), bs + C, bb + C, 96, 96,
                       (float*)nullptr);
    // 6-8. 48 level; L4 dual-writes net1
    hipLaunchKernelGGL((mconv_kernel<2, false, false>), mblk(n48), dim3(256), 0, stream,
                       P0h, P1h, m48, list, nact, WL(2), bs + 2 * C, bb + 2 * C, 96, 48,
                       (float*)nullptr);
    hipLaunchKernelGGL((mconv_kernel<1, false, false>), mblk(n48), dim3(256), 0, stream,
                       P1h, P0h, m48, list, nact, WL(3), bs + 3 * C, bb + 3 * C, 48, 48,
                       (float*)nullptr);
    hipLaunchKernelGGL((mconv_kernel<1, false, true>), mblk(n48), dim3(256), 0, stream,
                       P0h, P1h, m48, list, nact, WL(4), bs + 4 * C, bb + 4 * C, 48, 48,
                       out);
    // 9-12. 24 level; L8 dual-writes net2
    hipLaunchKernelGGL((mconv_kernel<2, false, false>), mblk(n24), dim3(256), 0, stream,
                       P1h, P0h, m24, list, nact, WL(5), bs + 5 * C, bb + 5 * C, 48, 24,
                       (float*)nullptr);
    hipLaunchKernelGGL((mconv_kernel<1, false, false>), mblk(n24), dim3(256), 0, stream,
                       P0h, P1h, m24, list, nact, WL(6), bs + 6 * C, bb + 6 * C, 24, 24,
                       (float*)nullptr);
    hipLaunchKernelGGL((mconv_kernel<1, false, false>), mblk(n24), dim3(256), 0, stream,
                       P1h, P0h, m24, list, nact, WL(7), bs + 7 * C, bb + 7 * C, 24, 24,
                       (float*)nullptr);
    hipLaunchKernelGGL((mconv_kernel<1, false, true>), mblk(n24), dim3(256), 0, stream,
                       P0h, P1h, m24, list, nact, WL(8), bs + 8 * C, bb + 8 * C, 24, 24,
                       out + (long)C * n48);
    // 13-16. 12 level; L12 dual-writes net3
    hipLaunchKernelGGL((mconv_kernel<2, false, false>), mblk(n12), dim3(256), 0, stream,
                       P1h, P0h, m12, list, nact, WL(9), bs + 9 * C, bb + 9 * C, 24, 12,
                       (float*)nullptr);
    hipLaunchKernelGGL((mconv_kernel<1, false, false>), mblk(n12), dim3(256), 0, stream,
                       P0h, P1h, m12, list, nact, WL(10), bs + 10 * C, bb + 10 * C, 12, 12,
                       (float*)nullptr);
    hipLaunchKernelGGL((mconv_kernel<1, false, false>), mblk(n12), dim3(256), 0, stream,
                       P1h, P0h, m12, list, nact, WL(11), bs + 11 * C, bb + 11 * C, 12, 12,
                       (float*)nullptr);
    hipLaunchKernelGGL((mconv_kernel<1, false, true>), mblk(n12), dim3(256), 0, stream,
                       P0h, P1h, m12, list, nact, WL(12), bs + 12 * C, bb + 12 * C, 12, 12,
                       out + (long)C * (n48 + n24));
    // 17-20. 6 level; L16 dual-writes net4
    hipLaunchKernelGGL((mconv_kernel<2, false, false>), mblk(n6), dim3(256), 0, stream,
                       P1h, P0h, m6, list, nact, WL(13), bs + 13 * C, bb + 13 * C, 12, 6,
                       (float*)nullptr);
    hipLaunchKernelGGL((mconv_kernel<1, false, false>), mblk(n6), dim3(256), 0, stream,
                       P0h, P1h, m6, list, nact, WL(14), bs + 14 * C, bb + 14 * C, 6, 6,
                       (float*)nullptr);
    hipLaunchKernelGGL((mconv_kernel<1, false, false>), mblk(n6), dim3(256), 0, stream,
                       P1h, P0h, m6, list, nact, WL(15), bs + 15 * C, bb + 15 * C, 6, 6,
                       (float*)nullptr);
    hipLaunchKernelGGL((mconv_kernel<1, false, true>), mblk(n6), dim3(256), 0, stream,
                       P0h, P1h, m6, list, nact, WL(16), bs + 16 * C, bb + 16 * C, 6, 6,
                       out + (long)C * (n48 + n24 + n12));
}

// Round 18
// 204.156 us; speedup vs baseline: 1.1093x; 1.1093x over previous
//
#include <hip/hip_runtime.h>

#define C 16
#define TAPS 27
#define NCONV 17
#define LISTCAP 98304
#define NPAIR 14

typedef _Float16 half8 __attribute__((ext_vector_type(8)));
typedef _Float16 half4 __attribute__((ext_vector_type(4)));
typedef float f32x4 __attribute__((ext_vector_type(4)));

// ---- prep: x NCDHW->NDHWC fp16, zero P1h, per-block counts, weights, m48 ----
// Wh[l][pair][lane][8]: lane co=lane&15, g=lane>>4; k=8g+j; ci=k&15; tap=2p+(k>>4).
__global__ void prep_kernel(const float* __restrict__ x, const int* __restrict__ mask_idx,
                            _Float16* __restrict__ P0h, _Float16* __restrict__ P1h,
                            const float* __restrict__ W, _Float16* __restrict__ Wh,
                            int* __restrict__ counts, float* __restrict__ m48) {
    const int n96 = 96 * 96 * 96;
    int b = blockIdx.x;
    if (b < 3456) {
        int v = b * 256 + threadIdx.x;  // n96 == 3456*256 exactly
        half8 h0, h1;
#pragma unroll
        for (int c = 0; c < 8; c++) h0[c] = (_Float16)x[(long)c * n96 + v];
#pragma unroll
        for (int c = 0; c < 8; c++) h1[c] = (_Float16)x[(long)(c + 8) * n96 + v];
        half8* dp = reinterpret_cast<half8*>(P0h + (long)v * C);
        dp[0] = h0;
        dp[1] = h1;
        half8 zz = {};
        half8* zp = reinterpret_cast<half8*>(P1h + (long)v * C);
        zp[0] = zz;
        zp[1] = zz;
        int act = (mask_idx[v] == 0);
        unsigned long long bl = __ballot(act);
        __shared__ int wsum[4];
        int wid = threadIdx.x >> 6, lane = threadIdx.x & 63;
        if (lane == 0) wsum[wid] = __popcll(bl);
        __syncthreads();
        if (threadIdx.x == 0) counts[b] = wsum[0] + wsum[1] + wsum[2] + wsum[3];
    } else if (b < 3456 + 476) {
        int i = (b - 3456) * 256 + threadIdx.x;
        const int total = NCONV * NPAIR * 64 * 8;
        if (i < total) {
            int j = i & 7;
            int lane = (i >> 3) & 63;
            int p = (i >> 9) % NPAIR;
            int l = (i >> 9) / NPAIR;
            int co = lane & 15;
            int g = lane >> 4;
            int k = 8 * g + j;
            int ci = k & 15;
            int tap = 2 * p + (k >> 4);
            float val = (tap < TAPS) ? W[((l * C + co) * C + ci) * TAPS + tap] : 0.f;
            Wh[i] = (_Float16)val;
        }
    } else {
        // m48: thread per voxel, 3^3 window over mask_idx at [2c-1, 2c+1]
        int i = (b - 3456 - 476) * 256 + threadIdx.x;  // 432*256 == 110592 exactly
        int xx = i % 48, yy = (i / 48) % 48, zc = i / (48 * 48);
        float m = 0.f;
        for (int dz = 0; dz < 3; dz++) {
            int z2 = 2 * zc - 1 + dz;
            if ((unsigned)z2 >= 96u) continue;
            for (int dy = 0; dy < 3; dy++) {
                int y2 = 2 * yy - 1 + dy;
                if ((unsigned)y2 >= 96u) continue;
                for (int dx = 0; dx < 3; dx++) {
                    int x2 = 2 * xx - 1 + dx;
                    if ((unsigned)x2 >= 96u) continue;
                    if (mask_idx[((long)z2 * 96 + y2) * 96 + x2] == 0) m = 1.f;
                }
            }
        }
        m48[i] = m;
    }
}

__global__ void scan_kernel(const int* __restrict__ counts, int* __restrict__ offsets,
                            int* __restrict__ nact, int nb) {
    __shared__ int s[256];
    int t = threadIdx.x;
    const int CH = (nb + 255) / 256;
    int base = t * CH, sum = 0;
    for (int j = 0; j < CH; j++)
        if (base + j < nb) sum += counts[base + j];
    s[t] = sum;
    __syncthreads();
    for (int off = 1; off < 256; off <<= 1) {
        int v = (t >= off) ? s[t - off] : 0;
        __syncthreads();
        s[t] += v;
        __syncthreads();
    }
    int run = s[t] - sum;
    for (int j = 0; j < CH; j++) {
        if (base + j < nb) {
            offsets[base + j] = run;
            run += counts[base + j];
        }
    }
    if (t == 255) *nact = s[255];
}

// ---- scatter + all remaining pools (m24 3^3, m12 7^3, m6 15^3 — all from m48) ----
__global__ void scatter_kernel(const int* __restrict__ mi, const int* __restrict__ offsets,
                               int* __restrict__ list, int cap, const float* __restrict__ m48,
                               float* __restrict__ m24, float* __restrict__ m12,
                               float* __restrict__ m6) {
    int b = blockIdx.x;
    int tid = threadIdx.x;
    if (b < 3456) {
        int i = b * 256 + tid;
        int act = (mi[i] == 0);
        unsigned long long bl = __ballot(act);
        __shared__ int wsum[4];
        int wid = tid >> 6, lane = tid & 63;
        if (lane == 0) wsum[wid] = __popcll(bl);
        __syncthreads();
        int wbase = 0;
        for (int w = 0; w < wid; w++) wbase += wsum[w];
        int prefix = __popcll(bl & ((1ull << lane) - 1));
        if (act) {
            int pos = offsets[b] + wbase + prefix;
            if (pos < cap) list[pos] = i;
        }
    } else if (b < 3456 + 54) {  // m24: thread/voxel, 3^3 over m48
        int i = (b - 3456) * 256 + tid;
        if (i < 24 * 24 * 24) {
            int x = i % 24, y = (i / 24) % 24, z = i / (24 * 24);
            float m = 0.f;
            for (int dz = 0; dz < 3; dz++) {
                int zz = 2 * z - 1 + dz;
                if ((unsigned)zz >= 48u) continue;
                for (int dy = 0; dy < 3; dy++) {
                    int yy = 2 * y - 1 + dy;
                    if ((unsigned)yy >= 48u) continue;
                    for (int dx = 0; dx < 3; dx++) {
                        int xx = 2 * x - 1 + dx;
                        if ((unsigned)xx >= 48u) continue;
                        m = fmaxf(m, m48[((long)zz * 48 + yy) * 48 + xx]);
                    }
                }
            }
            m24[i] = m;
        }
    } else if (b < 3456 + 54 + 432) {  // m12: wave/voxel, 7^3 over m48 at [4c-3,4c+3]
        int wv = (b - 3456 - 54) * 4 + (tid >> 6);
        int lane = tid & 63;
        int x = wv % 12, y = (wv / 12) % 12, z = wv / 144;
        float m = 0.f;
        for (int k = lane; k < 343; k += 64) {
            int dz = k / 49, r = k % 49, dy = r / 7, dx = r % 7;
            int zz = 4 * z - 3 + dz, yy = 4 * y - 3 + dy, xx = 4 * x - 3 + dx;
            if ((unsigned)zz < 48u && (unsigned)yy < 48u && (unsigned)xx < 48u)
                m = fmaxf(m, m48[((long)zz * 48 + yy) * 48 + xx]);
        }
        for (int off = 32; off; off >>= 1) m = fmaxf(m, __shfl_xor(m, off));
        if (lane == 0 && wv < 1728) m12[wv] = m;
    } else {  // m6: wave/voxel, 15^3 over m48 at [8c-7,8c+7]
        int wv = (b - 3456 - 54 - 432) * 4 + (tid >> 6);
        int lane = tid & 63;
        int x = wv % 6, y = (wv / 6) % 6, z = wv / 36;
        float m = 0.f;
        for (int k = lane; k < 3375; k += 64) {
            int dz = k / 225, r = k % 225, dy = r / 15, dx = r % 15;
            int zz = 8 * z - 7 + dz, yy = 8 * y - 7 + dy, xx = 8 * x - 7 + dx;
            if ((unsigned)zz < 48u && (unsigned)yy < 48u && (unsigned)xx < 48u)
                m = fmaxf(m, m48[((long)zz * 48 + yy) * 48 + xx]);
        }
        for (int off = 32; off; off >>= 1) m = fmaxf(m, __shfl_xor(m, off));
        if (lane == 0 && wv < 216) m6[wv] = m;
    }
}

// ---- MFMA conv (r13-proven) + optional fused fp32 NCDHW output ----
template <int STRIDE, bool SPARSE, bool WF32>
__global__ __launch_bounds__(256) void mconv_kernel(
    const _Float16* __restrict__ in, _Float16* __restrict__ out,
    const float* __restrict__ mask, const int* __restrict__ list,
    const int* __restrict__ nact, const _Float16* __restrict__ Whl,
    const float* __restrict__ bs, const float* __restrict__ bb,
    int Din, int Dout, float* __restrict__ outf) {
    int n = Dout * Dout * Dout;
    int nv;
    if (SPARSE) {
        nv = *nact;
        if (nv > LISTCAP) nv = LISTCAP;
    } else {
        nv = n;
    }
    int tile = blockIdx.x * 4 + (threadIdx.x >> 6);
    if (tile * 16 >= nv) return;  // per-wave exit (no barriers)

    int lane = threadIdx.x & 63;
    int col = lane & 15;
    int g = lane >> 4;
    int s = tile * 16 + col;
    bool val = s < nv;
    int v = 0;
    if (SPARSE) {
        if (val) v = list[s];
    } else {
        v = val ? s : 0;
    }
    int x = v % Dout, y = (v / Dout) % Dout, z = v / (Dout * Dout);

    const half8* wf = reinterpret_cast<const half8*>(Whl);
    half8 a[NPAIR];
#pragma unroll
    for (int p = 0; p < NPAIR; p++) a[p] = wf[p * 64 + lane];

    int half_off = (g & 1) * 8;
    int tg = g >> 1;

    f32x4 acc = {0.f, 0.f, 0.f, 0.f};
#pragma unroll
    for (int p = 0; p < NPAIR; p++) {
        int tap = 2 * p + tg;
        if (tap > TAPS - 1) tap = TAPS - 1;  // dummy half: weights are 0
        int kz = tap / 9, ky = (tap / 3) % 3, kx = tap % 3;
        int zz = STRIDE * z - 1 + kz;
        int yy = STRIDE * y - 1 + ky;
        int xx = STRIDE * x - 1 + kx;
        bool ok = val && ((unsigned)zz < (unsigned)Din) && ((unsigned)yy < (unsigned)Din) &&
                  ((unsigned)xx < (unsigned)Din);
        half8 b = {};
        if (ok) {
            b = *reinterpret_cast<const half8*>(
                in + (long)((zz * Din + yy) * Din + xx) * C + half_off);
        }
        acc = __builtin_amdgcn_mfma_f32_16x16x32_f16(a[p], b, acc, 0, 0, 0);
    }

    if (val) {
        float mk = SPARSE ? 1.f : mask[v];
        int cob = g * 4;
        half4 r;
#pragma unroll
        for (int j = 0; j < 4; j++) {
            float t = fmaxf(acc[j] * bs[cob + j] + bb[cob + j], 0.f) * mk;
            r[j] = (_Float16)t;
            if (WF32) outf[(long)(cob + j) * n + v] = t;
        }
        *reinterpret_cast<half4*>(out + (long)v * C + cob) = r;
    }
}

// ---- fused 6^3 level: 4 conv layers, ONE block of 16 waves (14 tiles => 1 round/layer) ----
__global__ __launch_bounds__(1024) void tail6_kernel(
    const _Float16* __restrict__ gin,  // 12^3 NDHWC fp16 (final 12-level activations)
    const float* __restrict__ m6, const _Float16* __restrict__ Wh,
    const float* __restrict__ bs, const float* __restrict__ bb,
    float* __restrict__ out4) {
    __shared__ _Float16 G0[216 * 16], G1[216 * 16];
    __shared__ float Lm6[216];

    int tid = threadIdx.x;
    int lane = tid & 63;
    int wid = tid >> 6;  // 0..15; tiles 0..13 active
    int col = lane & 15, g = lane >> 4;
    int ho = (g & 1) * 8, tg = g >> 1;

    for (int i = tid; i < 216; i += 1024) Lm6[i] = m6[i];
    __syncthreads();

    int s = wid * 16 + col;
    bool val = (wid < 14) && (s < 216);
    int v = val ? s : 0;
    int x = v % 6, y = (v / 6) % 6, z = v / 36;

    auto layer = [&](const _Float16* gsrc, const _Float16* lsrc, int Din, int stride,
                     int lidx, _Float16* lout, float* outf) {
        const half8* wf = reinterpret_cast<const half8*>(Wh + (long)lidx * NPAIR * 64 * 8);
        half8 a[NPAIR];
#pragma unroll
        for (int p = 0; p < NPAIR; p++) a[p] = wf[p * 64 + lane];
        f32x4 acc = {0.f, 0.f, 0.f, 0.f};
#pragma unroll
        for (int p = 0; p < NPAIR; p++) {
            int tap = 2 * p + tg;
            if (tap > TAPS - 1) tap = TAPS - 1;
            int kz = tap / 9, ky = (tap / 3) % 3, kx = tap % 3;
            int zz = stride * z - 1 + kz;
            int yy = stride * y - 1 + ky;
            int xx = stride * x - 1 + kx;
            bool ok = val && ((unsigned)zz < (unsigned)Din) && ((unsigned)yy < (unsigned)Din) &&
                      ((unsigned)xx < (unsigned)Din);
            half8 b = {};
            if (ok) {
                long off = (long)((zz * Din + yy) * Din + xx) * C + ho;
                b = gsrc ? *reinterpret_cast<const half8*>(gsrc + off)
                         : *reinterpret_cast<const half8*>(lsrc + off);
            }
            acc = __builtin_amdgcn_mfma_f32_16x16x32_f16(a[p], b, acc, 0, 0, 0);
        }
        if (val) {
            float mkv = Lm6[v];
            int cob = g * 4;
            const float* bsl = bs + lidx * C;
            const float* bbl = bb + lidx * C;
            half4 r;
#pragma unroll
            for (int j = 0; j < 4; j++) {
                float t = fmaxf(acc[j] * bsl[cob + j] + bbl[cob + j], 0.f) * mkv;
                r[j] = (_Float16)t;
                if (outf) outf[(long)(cob + j) * 216 + v] = t;
            }
            if (lout) *reinterpret_cast<half4*>(lout + (long)v * C + cob) = r;
        }
        __syncthreads();
    };

    layer(gin, nullptr, 12, 2, 13, G0, nullptr);   // down 12->6
    layer(nullptr, G0, 6, 1, 14, G1, nullptr);
    layer(nullptr, G1, 6, 1, 15, G0, nullptr);
    layer(nullptr, G0, 6, 1, 16, nullptr, out4);   // net4 (fp32 only)
}

extern "C" void kernel_launch(void* const* d_in, const int* in_sizes, int n_in,
                              void* d_out, int out_size, void* d_ws, size_t ws_size,
                              hipStream_t stream) {
    const float* x = (const float*)d_in[0];
    const int* mask_idx = (const int*)d_in[1];
    const float* W = (const float*)d_in[2];
    const float* bs = (const float*)d_in[3];
    const float* bb = (const float*)d_in[4];
    float* out = (float*)d_out;

    const int n96 = 96 * 96 * 96;
    const int n48 = 48 * 48 * 48;
    const int n24 = 24 * 24 * 24;
    const int n12 = 12 * 12 * 12;
    const int n6 = 6 * 6 * 6;
    const int NB = 3456;

    _Float16* P0h = (_Float16*)d_ws;
    _Float16* P1h = P0h + (long)C * n96;
    float* m48 = (float*)(P1h + (long)C * n96);
    float* m24 = m48 + n48;
    float* m12 = m24 + n24;
    float* m6 = m12 + n12;
    _Float16* Wh = (_Float16*)(m6 + n6);  // [17][14][64][8]
    int* list = (int*)(Wh + (long)NCONV * NPAIR * 64 * 8);
    int* counts = list + LISTCAP;
    int* offsets = counts + NB;
    int* nact = offsets + NB;

    // 1. prep (transpose + zero + counts + weights + m48)
    hipLaunchKernelGGL(prep_kernel, dim3(3456 + 476 + 432), dim3(256), 0, stream,
                       x, mask_idx, P0h, P1h, W, Wh, counts, m48);
    // 2. scan
    hipLaunchKernelGGL(scan_kernel, dim3(1), dim3(256), 0, stream, counts, offsets, nact, NB);
    // 3. scatter + pools (m24, m12, m6 all from m48)
    hipLaunchKernelGGL(scatter_kernel, dim3(3456 + 54 + 432 + 54), dim3(256), 0, stream,
                       mask_idx, offsets, list, LISTCAP, m48, m24, m12, m6);

    auto mblk = [&](long nvox) { return dim3((unsigned)((nvox + 63) / 64)); };
    auto WL = [&](int l) { return Wh + (long)l * NPAIR * 64 * 8; };

    // 4-5. sparse 96 level
    hipLaunchKernelGGL((mconv_kernel<1, true, false>), mblk(LISTCAP), dim3(256), 0, stream,
                       P0h, P1h, (const float*)nullptr, list, nact, WL(0), bs, bb, 96, 96,
                       (float*)nullptr);
    hipLaunchKernelGGL((mconv_kernel<1, true, false>), mblk(LISTCAP), dim3(256), 0, stream,
                       P1h, P0h, (const float*)nullptr, list, nact, WL(1), bs + C, bb + C, 96, 96,
                       (float*)nullptr);
    // 6-8. 48 level; L4 dual-writes net1
    hipLaunchKernelGGL((mconv_kernel<2, false, false>), mblk(n48), dim3(256), 0, stream,
                       P0h, P1h, m48, list, nact, WL(2), bs + 2 * C, bb + 2 * C, 96, 48,
                       (float*)nullptr);
    hipLaunchKernelGGL((mconv_kernel<1, false, false>), mblk(n48), dim3(256), 0, stream,
                       P1h, P0h, m48, list, nact, WL(3), bs + 3 * C, bb + 3 * C, 48, 48,
                       (float*)nullptr);
    hipLaunchKernelGGL((mconv_kernel<1, false, true>), mblk(n48), dim3(256), 0, stream,
                       P0h, P1h, m48, list, nact, WL(4), bs + 4 * C, bb + 4 * C, 48, 48,
                       out);
    // 9-12. 24 level; L8 dual-writes net2
    hipLaunchKernelGGL((mconv_kernel<2, false, false>), mblk(n24), dim3(256), 0, stream,
                       P1h, P0h, m24, list, nact, WL(5), bs + 5 * C, bb + 5 * C, 48, 24,
                       (float*)nullptr);
    hipLaunchKernelGGL((mconv_kernel<1, false, false>), mblk(n24), dim3(256), 0, stream,
                       P0h, P1h, m24, list, nact, WL(6), bs + 6 * C, bb + 6 * C, 24, 24,
                       (float*)nullptr);
    hipLaunchKernelGGL((mconv_kernel<1, false, false>), mblk(n24), dim3(256), 0, stream,
                       P1h, P0h, m24, list, nact, WL(7), bs + 7 * C, bb + 7 * C, 24, 24,
                       (float*)nullptr);
    hipLaunchKernelGGL((mconv_kernel<1, false, true>), mblk(n24), dim3(256), 0, stream,
                       P0h, P1h, m24, list, nact, WL(8), bs + 8 * C, bb + 8 * C, 24, 24,
                       out + (long)C * n48);
    // 13-16. 12 level; L12 dual-writes net3
    hipLaunchKernelGGL((mconv_kernel<2, false, false>), mblk(n12), dim3(256), 0, stream,
                       P1h, P0h, m12, list, nact, WL(9), bs + 9 * C, bb + 9 * C, 24, 12,
                       (float*)nullptr);
    hipLaunchKernelGGL((mconv_kernel<1, false, false>), mblk(n12), dim3(256), 0, stream,
                       P0h, P1h, m12, list, nact, WL(10), bs + 10 * C, bb + 10 * C, 12, 12,
                       (float*)nullptr);
    hipLaunchKernelGGL((mconv_kernel<1, false, false>), mblk(n12), dim3(256), 0, stream,
                       P1h, P0h, m12, list, nact, WL(11), bs + 11 * C, bb + 11 * C, 12, 12,
                       (float*)nullptr);
    hipLaunchKernelGGL((mconv_kernel<1, false, true>), mblk(n12), dim3(256), 0, stream,
                       P0h, P1h, m12, list, nact, WL(12), bs + 12 * C, bb + 12 * C, 12, 12,
                       out + (long)C * (n48 + n24));
    // 17. fused 6 level (layers 13-16; net4)
    hipLaunchKernelGGL(tail6_kernel, dim3(1), dim3(1024), 0, stream,
                       P1h, m6, Wh, bs, bb, out + (long)C * (n48 + n24 + n12));
}

// Round 19
// 195.662 us; speedup vs baseline: 1.1575x; 1.0434x over previous
//
#include <hip/hip_runtime.h>

#define C 16
#define TAPS 27
#define NCONV 17
#define LISTCAP 98304
#define NPAIR 14

typedef _Float16 half8 __attribute__((ext_vector_type(8)));
typedef _Float16 half4 __attribute__((ext_vector_type(4)));
typedef float f32x4 __attribute__((ext_vector_type(4)));

// ---- prep: weights, m48, brickless counts + inv=-1 init ----
// Wh[l][pair][lane][8]: lane co=lane&15, g=lane>>4; k=8g+j; ci=k&15; tap=2p+(k>>4).
__global__ void prep_kernel(const int* __restrict__ mask_idx, const float* __restrict__ W,
                            _Float16* __restrict__ Wh, int* __restrict__ counts,
                            float* __restrict__ m48, int* __restrict__ inv) {
    int b = blockIdx.x;
    if (b < 476) {
        int i = b * 256 + threadIdx.x;
        const int total = NCONV * NPAIR * 64 * 8;
        if (i < total) {
            int j = i & 7;
            int lane = (i >> 3) & 63;
            int p = (i >> 9) % NPAIR;
            int l = (i >> 9) / NPAIR;
            int co = lane & 15;
            int g = lane >> 4;
            int k = 8 * g + j;
            int ci = k & 15;
            int tap = 2 * p + (k >> 4);
            float val = (tap < TAPS) ? W[((l * C + co) * C + ci) * TAPS + tap] : 0.f;
            Wh[i] = (_Float16)val;
        }
    } else if (b < 476 + 432) {
        // m48: thread per voxel, 3^3 window over mask_idx at [2c-1, 2c+1]
        int i = (b - 476) * 256 + threadIdx.x;  // 432*256 == 110592
        int xx = i % 48, yy = (i / 48) % 48, zc = i / (48 * 48);
        float m = 0.f;
        for (int dz = 0; dz < 3; dz++) {
            int z2 = 2 * zc - 1 + dz;
            if ((unsigned)z2 >= 96u) continue;
            for (int dy = 0; dy < 3; dy++) {
                int y2 = 2 * yy - 1 + dy;
                if ((unsigned)y2 >= 96u) continue;
                for (int dx = 0; dx < 3; dx++) {
                    int x2 = 2 * xx - 1 + dx;
                    if ((unsigned)x2 >= 96u) continue;
                    if (mask_idx[((long)z2 * 96 + y2) * 96 + x2] == 0) m = 1.f;
                }
            }
        }
        m48[i] = m;
    } else {
        // counts + inv init (3456 blocks)
        int v = (b - 476 - 432) * 256 + threadIdx.x;
        inv[v] = -1;
        int act = (mask_idx[v] == 0);
        unsigned long long bl = __ballot(act);
        __shared__ int wsum[4];
        int wid = threadIdx.x >> 6, lane = threadIdx.x & 63;
        if (lane == 0) wsum[wid] = __popcll(bl);
        __syncthreads();
        if (threadIdx.x == 0) counts[b - 476 - 432] = wsum[0] + wsum[1] + wsum[2] + wsum[3];
    }
}

__global__ void scan_kernel(const int* __restrict__ counts, int* __restrict__ offsets,
                            int* __restrict__ nact, int nb) {
    __shared__ int s[256];
    int t = threadIdx.x;
    const int CH = (nb + 255) / 256;
    int base = t * CH, sum = 0;
    for (int j = 0; j < CH; j++)
        if (base + j < nb) sum += counts[base + j];
    s[t] = sum;
    __syncthreads();
    for (int off = 1; off < 256; off <<= 1) {
        int v = (t >= off) ? s[t - off] : 0;
        __syncthreads();
        s[t] += v;
        __syncthreads();
    }
    int run = s[t] - sum;
    for (int j = 0; j < CH; j++) {
        if (base + j < nb) {
            offsets[base + j] = run;
            run += counts[base + j];
        }
    }
    if (t == 255) *nact = s[255];
}

// ---- scatter (list + inv) + pools (m24 3^3, m12 7^3, m6 15^3 — from m48) ----
__global__ void scatter_kernel(const int* __restrict__ mi, const int* __restrict__ offsets,
                               int* __restrict__ list, int* __restrict__ inv, int cap,
                               const float* __restrict__ m48, float* __restrict__ m24,
                               float* __restrict__ m12, float* __restrict__ m6) {
    int b = blockIdx.x;
    int tid = threadIdx.x;
    if (b < 3456) {
        int i = b * 256 + tid;
        int act = (mi[i] == 0);
        unsigned long long bl = __ballot(act);
        __shared__ int wsum[4];
        int wid = tid >> 6, lane = tid & 63;
        if (lane == 0) wsum[wid] = __popcll(bl);
        __syncthreads();
        int wbase = 0;
        for (int w = 0; w < wid; w++) wbase += wsum[w];
        int prefix = __popcll(bl & ((1ull << lane) - 1));
        if (act) {
            int pos = offsets[b] + wbase + prefix;
            if (pos < cap) {
                list[pos] = i;
                inv[i] = pos;
            }
        }
    } else if (b < 3456 + 54) {  // m24
        int i = (b - 3456) * 256 + tid;
        if (i < 24 * 24 * 24) {
            int x = i % 24, y = (i / 24) % 24, z = i / (24 * 24);
            float m = 0.f;
            for (int dz = 0; dz < 3; dz++) {
                int zz = 2 * z - 1 + dz;
                if ((unsigned)zz >= 48u) continue;
                for (int dy = 0; dy < 3; dy++) {
                    int yy = 2 * y - 1 + dy;
                    if ((unsigned)yy >= 48u) continue;
                    for (int dx = 0; dx < 3; dx++) {
                        int xx = 2 * x - 1 + dx;
                        if ((unsigned)xx >= 48u) continue;
                        m = fmaxf(m, m48[((long)zz * 48 + yy) * 48 + xx]);
                    }
                }
            }
            m24[i] = m;
        }
    } else if (b < 3456 + 54 + 432) {  // m12: wave/voxel, 7^3 over m48
        int wv = (b - 3456 - 54) * 4 + (tid >> 6);
        int lane = tid & 63;
        int x = wv % 12, y = (wv / 12) % 12, z = wv / 144;
        float m = 0.f;
        for (int k = lane; k < 343; k += 64) {
            int dz = k / 49, r = k % 49, dy = r / 7, dx = r % 7;
            int zz = 4 * z - 3 + dz, yy = 4 * y - 3 + dy, xx = 4 * x - 3 + dx;
            if ((unsigned)zz < 48u && (unsigned)yy < 48u && (unsigned)xx < 48u)
                m = fmaxf(m, m48[((long)zz * 48 + yy) * 48 + xx]);
        }
        for (int off = 32; off; off >>= 1) m = fmaxf(m, __shfl_xor(m, off));
        if (lane == 0 && wv < 1728) m12[wv] = m;
    } else {  // m6: wave/voxel, 15^3 over m48
        int wv = (b - 3456 - 54 - 432) * 4 + (tid >> 6);
        int lane = tid & 63;
        int x = wv % 6, y = (wv / 6) % 6, z = wv / 36;
        float m = 0.f;
        for (int k = lane; k < 3375; k += 64) {
            int dz = k / 225, r = k % 225, dy = r / 15, dx = r % 15;
            int zz = 8 * z - 7 + dz, yy = 8 * y - 7 + dy, xx = 8 * x - 7 + dx;
            if ((unsigned)zz < 48u && (unsigned)yy < 48u && (unsigned)xx < 48u)
                m = fmaxf(m, m48[((long)zz * 48 + yy) * 48 + xx]);
        }
        for (int off = 32; off; off >>= 1) m = fmaxf(m, __shfl_xor(m, off));
        if (lane == 0 && wv < 216) m6[wv] = m;
    }
}

// ---- compact transpose (x -> Xc fp16) + neighbor table nbr[tap][s] ----
__global__ void compactx_kernel(const float* __restrict__ x, const int* __restrict__ list,
                                const int* __restrict__ nact, const int* __restrict__ inv,
                                _Float16* __restrict__ Xc, int* __restrict__ nbr) {
    const int n96 = 96 * 96 * 96;
    int nv = *nact;
    if (nv > LISTCAP) nv = LISTCAP;
    int s = blockIdx.x * 256 + threadIdx.x;
    if (s >= nv) return;
    int v = list[s];
    half8 h0, h1;
#pragma unroll
    for (int c = 0; c < 8; c++) h0[c] = (_Float16)x[(long)c * n96 + v];
#pragma unroll
    for (int c = 0; c < 8; c++) h1[c] = (_Float16)x[(long)(c + 8) * n96 + v];
    half8* dp = reinterpret_cast<half8*>(Xc + (long)s * C);
    dp[0] = h0;
    dp[1] = h1;
    int xx = v % 96, yy = (v / 96) % 96, zz = v / (96 * 96);
    for (int t = 0; t < TAPS; t++) {
        int kz = t / 9, ky = (t / 3) % 3, kx = t % 3;
        int z2 = zz - 1 + kz, y2 = yy - 1 + ky, x2 = xx - 1 + kx;
        int idx = -1;
        if ((unsigned)z2 < 96u && (unsigned)y2 < 96u && (unsigned)x2 < 96u)
            idx = inv[((long)z2 * 96 + y2) * 96 + x2];
        nbr[t * LISTCAP + s] = idx;
    }
}

// ---- sparse conv over compacted activations (nbr-indexed gather) ----
__global__ __launch_bounds__(256) void sconv_kernel(
    const _Float16* __restrict__ Ain, _Float16* __restrict__ Aout,
    const int* __restrict__ nbr, const int* __restrict__ nact,
    const _Float16* __restrict__ Whl, const float* __restrict__ bs,
    const float* __restrict__ bb) {
    int nv = *nact;
    if (nv > LISTCAP) nv = LISTCAP;
    int tile = blockIdx.x * 4 + (threadIdx.x >> 6);
    if (tile * 16 >= nv) return;

    int lane = threadIdx.x & 63;
    int col = lane & 15;
    int g = lane >> 4;
    int s = tile * 16 + col;
    bool val = s < nv;

    const half8* wf = reinterpret_cast<const half8*>(Whl);
    half8 a[NPAIR];
#pragma unroll
    for (int p = 0; p < NPAIR; p++) a[p] = wf[p * 64 + lane];

    int half_off = (g & 1) * 8;
    int tg = g >> 1;

    f32x4 acc = {0.f, 0.f, 0.f, 0.f};
#pragma unroll
    for (int p = 0; p < NPAIR; p++) {
        int tap = 2 * p + tg;
        if (tap > TAPS - 1) tap = TAPS - 1;  // dummy half: weights are 0
        int idx = -1;
        if (val) idx = nbr[tap * LISTCAP + s];
        half8 b = {};
        if (idx >= 0) b = *reinterpret_cast<const half8*>(Ain + (long)idx * C + half_off);
        acc = __builtin_amdgcn_mfma_f32_16x16x32_f16(a[p], b, acc, 0, 0, 0);
    }

    if (val) {
        int cob = g * 4;
        half4 r;
#pragma unroll
        for (int j = 0; j < 4; j++)
            r[j] = (_Float16)fmaxf(acc[j] * bs[cob + j] + bb[cob + j], 0.f);
        *reinterpret_cast<half4*>(Aout + (long)s * C + cob) = r;
    }
}

// ---- down 96->48 reading compacted A via inv; writes dense 48^3 NDHWC ----
__global__ __launch_bounds__(256) void dconv_inv_kernel(
    const _Float16* __restrict__ Ain, _Float16* __restrict__ out,
    const float* __restrict__ mask, const int* __restrict__ inv,
    const _Float16* __restrict__ Whl, const float* __restrict__ bs,
    const float* __restrict__ bb) {
    const int n = 48 * 48 * 48;
    int tile = blockIdx.x * 4 + (threadIdx.x >> 6);
    if (tile * 16 >= n) return;
    int lane = threadIdx.x & 63;
    int col = lane & 15;
    int g = lane >> 4;
    int v = tile * 16 + col;  // < n always (n divisible by 16)
    int x = v % 48, y = (v / 48) % 48, z = v / (48 * 48);

    const half8* wf = reinterpret_cast<const half8*>(Whl);
    half8 a[NPAIR];
#pragma unroll
    for (int p = 0; p < NPAIR; p++) a[p] = wf[p * 64 + lane];
    int half_off = (g & 1) * 8;
    int tg = g >> 1;

    f32x4 acc = {0.f, 0.f, 0.f, 0.f};
#pragma unroll
    for (int p = 0; p < NPAIR; p++) {
        int tap = 2 * p + tg;
        if (tap > TAPS - 1) tap = TAPS - 1;
        int kz = tap / 9, ky = (tap / 3) % 3, kx = tap % 3;
        int zz = 2 * z - 1 + kz, yy = 2 * y - 1 + ky, xx = 2 * x - 1 + kx;
        int idx = -1;
        if ((unsigned)zz < 96u && (unsigned)yy < 96u && (unsigned)xx < 96u)
            idx = inv[((long)zz * 96 + yy) * 96 + xx];
        half8 b = {};
        if (idx >= 0) b = *reinterpret_cast<const half8*>(Ain + (long)idx * C + half_off);
        acc = __builtin_amdgcn_mfma_f32_16x16x32_f16(a[p], b, acc, 0, 0, 0);
    }

    float mk = mask[v];
    int cob = g * 4;
    half4 r;
#pragma unroll
    for (int j = 0; j < 4; j++)
        r[j] = (_Float16)(fmaxf(acc[j] * bs[cob + j] + bb[cob + j], 0.f) * mk);
    *reinterpret_cast<half4*>(out + (long)v * C + cob) = r;
}

// ---- dense MFMA conv (r13-proven) + optional fused fp32 NCDHW output ----
template <int STRIDE, bool WF32>
__global__ __launch_bounds__(256) void mconv_kernel(
    const _Float16* __restrict__ in, _Float16* __restrict__ out,
    const float* __restrict__ mask, const _Float16* __restrict__ Whl,
    const float* __restrict__ bs, const float* __restrict__ bb,
    int Din, int Dout, float* __restrict__ outf) {
    int n = Dout * Dout * Dout;
    int tile = blockIdx.x * 4 + (threadIdx.x >> 6);
    if (tile * 16 >= n) return;

    int lane = threadIdx.x & 63;
    int col = lane & 15;
    int g = lane >> 4;
    int s = tile * 16 + col;
    bool val = s < n;
    int v = val ? s : 0;
    int x = v % Dout, y = (v / Dout) % Dout, z = v / (Dout * Dout);

    const half8* wf = reinterpret_cast<const half8*>(Whl);
    half8 a[NPAIR];
#pragma unroll
    for (int p = 0; p < NPAIR; p++) a[p] = wf[p * 64 + lane];

    int half_off = (g & 1) * 8;
    int tg = g >> 1;

    f32x4 acc = {0.f, 0.f, 0.f, 0.f};
#pragma unroll
    for (int p = 0; p < NPAIR; p++) {
        int tap = 2 * p + tg;
        if (tap > TAPS - 1) tap = TAPS - 1;
        int kz = tap / 9, ky = (tap / 3) % 3, kx = tap % 3;
        int zz = STRIDE * z - 1 + kz;
        int yy = STRIDE * y - 1 + ky;
        int xx = STRIDE * x - 1 + kx;
        bool ok = val && ((unsigned)zz < (unsigned)Din) && ((unsigned)yy < (unsigned)Din) &&
                  ((unsigned)xx < (unsigned)Din);
        half8 b = {};
        if (ok) {
            b = *reinterpret_cast<const half8*>(
                in + (long)((zz * Din + yy) * Din + xx) * C + half_off);
        }
        acc = __builtin_amdgcn_mfma_f32_16x16x32_f16(a[p], b, acc, 0, 0, 0);
    }

    if (val) {
        float mk = mask[v];
        int cob = g * 4;
        half4 r;
#pragma unroll
        for (int j = 0; j < 4; j++) {
            float t = fmaxf(acc[j] * bs[cob + j] + bb[cob + j], 0.f) * mk;
            r[j] = (_Float16)t;
            if (WF32) outf[(long)(cob + j) * n + v] = t;
        }
        *reinterpret_cast<half4*>(out + (long)v * C + cob) = r;
    }
}

// ---- fused 6^3 level: 4 conv layers, ONE block of 16 waves ----
__global__ __launch_bounds__(1024) void tail6_kernel(
    const _Float16* __restrict__ gin, const float* __restrict__ m6,
    const _Float16* __restrict__ Wh, const float* __restrict__ bs,
    const float* __restrict__ bb, float* __restrict__ out4) {
    __shared__ _Float16 G0[216 * 16], G1[216 * 16];
    __shared__ float Lm6[216];

    int tid = threadIdx.x;
    int lane = tid & 63;
    int wid = tid >> 6;
    int col = lane & 15, g = lane >> 4;
    int ho = (g & 1) * 8, tg = g >> 1;

    for (int i = tid; i < 216; i += 1024) Lm6[i] = m6[i];
    __syncthreads();

    int s = wid * 16 + col;
    bool val = (wid < 14) && (s < 216);
    int v = val ? s : 0;
    int x = v % 6, y = (v / 6) % 6, z = v / 36;

    auto layer = [&](const _Float16* gsrc, const _Float16* lsrc, int Din, int stride,
                     int lidx, _Float16* lout, float* outf) {
        const half8* wf = reinterpret_cast<const half8*>(Wh + (long)lidx * NPAIR * 64 * 8);
        half8 a[NPAIR];
#pragma unroll
        for (int p = 0; p < NPAIR; p++) a[p] = wf[p * 64 + lane];
        f32x4 acc = {0.f, 0.f, 0.f, 0.f};
#pragma unroll
        for (int p = 0; p < NPAIR; p++) {
            int tap = 2 * p + tg;
            if (tap > TAPS - 1) tap = TAPS - 1;
            int kz = tap / 9, ky = (tap / 3) % 3, kx = tap % 3;
            int zz = stride * z - 1 + kz;
            int yy = stride * y - 1 + ky;
            int xx = stride * x - 1 + kx;
            bool ok = val && ((unsigned)zz < (unsigned)Din) && ((unsigned)yy < (unsigned)Din) &&
                      ((unsigned)xx < (unsigned)Din);
            half8 b = {};
            if (ok) {
                long off = (long)((zz * Din + yy) * Din + xx) * C + ho;
                b = gsrc ? *reinterpret_cast<const half8*>(gsrc + off)
                         : *reinterpret_cast<const half8*>(lsrc + off);
            }
            acc = __builtin_amdgcn_mfma_f32_16x16x32_f16(a[p], b, acc, 0, 0, 0);
        }
        if (val) {
            float mkv = Lm6[v];
            int cob = g * 4;
            const float* bsl = bs + lidx * C;
            const float* bbl = bb + lidx * C;
            half4 r;
#pragma unroll
            for (int j = 0; j < 4; j++) {
                float t = fmaxf(acc[j] * bsl[cob + j] + bbl[cob + j], 0.f) * mkv;
                r[j] = (_Float16)t;
                if (outf) outf[(long)(cob + j) * 216 + v] = t;
            }
            if (lout) *reinterpret_cast<half4*>(lout + (long)v * C + cob) = r;
        }
        __syncthreads();
    };

    layer(gin, nullptr, 12, 2, 13, G0, nullptr);
    layer(nullptr, G0, 6, 1, 14, G1, nullptr);
    layer(nullptr, G1, 6, 1, 15, G0, nullptr);
    layer(nullptr, G0, 6, 1, 16, nullptr, out4);
}

extern "C" void kernel_launch(void* const* d_in, const int* in_sizes, int n_in,
                              void* d_out, int out_size, void* d_ws, size_t ws_size,
                              hipStream_t stream) {
    const float* x = (const float*)d_in[0];
    const int* mask_idx = (const int*)d_in[1];
    const float* W = (const float*)d_in[2];
    const float* bs = (const float*)d_in[3];
    const float* bb = (const float*)d_in[4];
    float* out = (float*)d_out;

    const int n96 = 96 * 96 * 96;
    const int n48 = 48 * 48 * 48;
    const int n24 = 24 * 24 * 24;
    const int n12 = 12 * 12 * 12;
    const int n6 = 6 * 6 * 6;
    const int NB = 3456;

    float* m48 = (float*)d_ws;
    float* m24 = m48 + n48;
    float* m12 = m24 + n24;
    float* m6 = m12 + n12;
    _Float16* Wh = (_Float16*)(m6 + n6);  // [17][14][64][8]
    int* list = (int*)(Wh + (long)NCONV * NPAIR * 64 * 8);
    int* counts = list + LISTCAP;
    int* offsets = counts + NB;
    int* nact = offsets + NB;
    int* inv = nact + 1;                    // n96 ints
    int* nbr = inv + n96;                   // 27*LISTCAP ints
    _Float16* Xc = (_Float16*)(nbr + TAPS * LISTCAP);
    _Float16* A1 = Xc + (long)LISTCAP * C;
    _Float16* A2 = A1 + (long)LISTCAP * C;
    _Float16* P0h = A2 + (long)LISTCAP * C;  // dense ping-pong (<= 48^3 * C)
    _Float16* P1h = P0h + (long)n48 * C;

    // 1. prep: weights + m48 + counts + inv=-1
    hipLaunchKernelGGL(prep_kernel, dim3(476 + 432 + 3456), dim3(256), 0, stream,
                       mask_idx, W, Wh, counts, m48, inv);
    // 2. scan
    hipLaunchKernelGGL(scan_kernel, dim3(1), dim3(256), 0, stream, counts, offsets, nact, NB);
    // 3. scatter (list+inv) + pools
    hipLaunchKernelGGL(scatter_kernel, dim3(3456 + 54 + 432 + 54), dim3(256), 0, stream,
                       mask_idx, offsets, list, inv, LISTCAP, m48, m24, m12, m6);
    // 4. compact transpose + neighbor table
    hipLaunchKernelGGL(compactx_kernel, dim3(LISTCAP / 256), dim3(256), 0, stream,
                       x, list, nact, inv, Xc, nbr);

    auto mblk = [&](long nvox) { return dim3((unsigned)((nvox + 63) / 64)); };
    auto WL = [&](int l) { return Wh + (long)l * NPAIR * 64 * 8; };

    // 5-6. sparse 96 level (compacted)
    hipLaunchKernelGGL(sconv_kernel, mblk(LISTCAP), dim3(256), 0, stream,
                       Xc, A1, nbr, nact, WL(0), bs, bb);
    hipLaunchKernelGGL(sconv_kernel, mblk(LISTCAP), dim3(256), 0, stream,
                       A1, A2, nbr, nact, WL(1), bs + C, bb + C);
    // 7. down 96->48 via inv
    hipLaunchKernelGGL(dconv_inv_kernel, mblk(n48), dim3(256), 0, stream,
                       A2, P1h, m48, inv, WL(2), bs + 2 * C, bb + 2 * C);
    // 8-9. 48 level subm; L4 dual-writes net1
    hipLaunchKernelGGL((mconv_kernel<1, false>), mblk(n48), dim3(256), 0, stream,
                       P1h, P0h, m48, WL(3), bs + 3 * C, bb + 3 * C, 48, 48, (float*)nullptr);
    hipLaunchKernelGGL((mconv_kernel<1, true>), mblk(n48), dim3(256), 0, stream,
                       P0h, P1h, m48, WL(4), bs + 4 * C, bb + 4 * C, 48, 48, out);
    // 10-13. 24 level; L8 dual-writes net2
    hipLaunchKernelGGL((mconv_kernel<2, false>), mblk(n24), dim3(256), 0, stream,
                       P1h, P0h, m24, WL(5), bs + 5 * C, bb + 5 * C, 48, 24, (float*)nullptr);
    hipLaunchKernelGGL((mconv_kernel<1, false>), mblk(n24), dim3(256), 0, stream,
                       P0h, P1h, m24, WL(6), bs + 6 * C, bb + 6 * C, 24, 24, (float*)nullptr);
    hipLaunchKernelGGL((mconv_kernel<1, false>), mblk(n24), dim3(256), 0, stream,
                       P1h, P0h, m24, WL(7), bs + 7 * C, bb + 7 * C, 24, 24, (float*)nullptr);
    hipLaunchKernelGGL((mconv_kernel<1, true>), mblk(n24), dim3(256), 0, stream,
                       P0h, P1h, m24, WL(8), bs + 8 * C, bb + 8 * C, 24, 24, out + (long)C * n48);
    // 14-17. 12 level; L12 dual-writes net3
    hipLaunchKernelGGL((mconv_kernel<2, false>), mblk(n12), dim3(256), 0, stream,
                       P1h, P0h, m12, WL(9), bs + 9 * C, bb + 9 * C, 24, 12, (float*)nullptr);
    hipLaunchKernelGGL((mconv_kernel<1, false>), mblk(n12), dim3(256), 0, stream,
                       P0h, P1h, m12, WL(10), bs + 10 * C, bb + 10 * C, 12, 12, (float*)nullptr);
    hipLaunchKernelGGL((mconv_kernel<1, false>), mblk(n12), dim3(256), 0, stream,
                       P1h, P0h, m12, WL(11), bs + 11 * C, bb + 11 * C, 12, 12, (float*)nullptr);
    hipLaunchKernelGGL((mconv_kernel<1, true>), mblk(n12), dim3(256), 0, stream,
                       P0h, P1h, m12, WL(12), bs + 12 * C, bb + 12 * C, 12, 12,
                       out + (long)C * (n48 + n24));
    // 18. fused 6 level (layers 13-16; net4)
    hipLaunchKernelGGL(tail6_kernel, dim3(1), dim3(1024), 0, stream,
                       P1h, m6, Wh, bs, bb, out + (long)C * (n48 + n24 + n12));
}